// Round 6
// baseline (87.229 us; speedup 1.0000x reference)
//
#include <hip/hip_runtime.h>
#include <hip/hip_bf16.h>

typedef __attribute__((ext_vector_type(8))) short bf16x8;
typedef __attribute__((ext_vector_type(4))) float f32x4;

#define GRU_B 131072
#define BM 64

static __device__ __forceinline__ ushort f2bf(float f) {
  union { float f; unsigned u; } v; v.f = f;
  unsigned r = v.u + 0x7FFFu + ((v.u >> 16) & 1u);   // RNE
  return (ushort)(r >> 16);
}
static __device__ __forceinline__ float bf2f(ushort u) {
  union { unsigned u; float f; } v; v.u = ((unsigned)u) << 16;
  return v.f;
}
static __device__ __forceinline__ unsigned pk2(float a, float b) {
  float2 t; t.x = a; t.y = b;
  __hip_bfloat162 r = __float22bfloat162_rn(t);      // v_cvt_pk_bf16_f32
  union { __hip_bfloat162 b; unsigned u; } cv; cv.b = r;
  return cv.u;
}
static __device__ __forceinline__ float fsig(float x) {
  return __builtin_amdgcn_rcpf(1.0f + __expf(-x));
}
static __device__ __forceinline__ float ftanh(float x) {
  return 1.0f - 2.0f * __builtin_amdgcn_rcpf(1.0f + __expf(2.0f * x));
}
static __device__ __forceinline__ f32x4 splat4(float s) {
  f32x4 v = {s, s, s, s}; return v;
}

// Pack six 128x128 fp32 weight matrices into per-lane MFMA B-fragment order:
// chunk = ((mat*8 + cb)*4 + kb), 1KB each; within chunk lane*16B holds
// w[kb*32 + (lane>>4)*8 + e][cb*16 + (lane&15)], e=0..7, bf16.
// A B-frag load is ONE coalesced global_load_dwordx4 at chunk + lane*16.
__global__ void wtrans_kernel(const float* __restrict__ wz, const float* __restrict__ uz,
                              const float* __restrict__ wr, const float* __restrict__ ur,
                              const float* __restrict__ wh, const float* __restrict__ uh,
                              ushort* __restrict__ outw) {
  int f = blockIdx.x * 256 + threadIdx.x;          // 0..98303 (coalesced write)
  int mat = f >> 14;
  int rem = f & 16383;
  int chunk = rem >> 9;                            // 0..31
  int lane = (rem >> 3) & 63;
  int e = rem & 7;
  int cb = chunk >> 2, k0b = chunk & 3;
  int n = cb * 16 + (lane & 15);
  int k = k0b * 32 + (lane >> 4) * 8 + e;
  const float* src = (mat == 0) ? wz : (mat == 1) ? uz : (mat == 2) ? wr
                   : (mat == 3) ? ur : (mat == 4) ? wh : uh;
  outw[f] = f2bf(src[k * 128 + n]);
}

#define MFMA __builtin_amdgcn_mfma_f32_16x16x32_bf16

__global__ __launch_bounds__(256, 4) void gru_kernel(
    const float* __restrict__ x, const float* __restrict__ hprev,
    const ushort* __restrict__ wt,
    const float* __restrict__ bz, const float* __restrict__ br,
    const float* __restrict__ bh, float* __restrict__ out) {
  // 48 KB: xs[0..16K) hs[16K..32K) rhs[32K..48K); f32 out-tile reuses [0..32K)
  __shared__ __align__(16) char smem[49152];
  ushort* xs  = (ushort*)smem;
  ushort* hs  = (ushort*)(smem + 16384);
  ushort* rhs = (ushort*)(smem + 32768);

  const int tid = threadIdx.x;
  const int lane = tid & 63;
  const int wid = tid >> 6;          // 4 waves: column partition (32 cols each)
  const int l15 = lane & 15;
  const int q = lane >> 4;
  const long row0 = (long)blockIdx.x * BM;
  const int n0 = wid * 32;

  // per-lane biases (folded into accumulator init)
  float brv0 = br[n0 + l15], brv1 = br[n0 + 16 + l15];
  float bzv0 = bz[n0 + l15], bzv1 = bz[n0 + 16 + l15];
  float bhv0 = bh[n0 + l15], bhv1 = bh[n0 + 16 + l15];

  const ushort* wlane = wt + (lane << 3);
  auto wfrag = [&](int mat, int nc, int kb) -> const bf16x8* {
    return (const bf16x8*)(wlane + (((((mat << 3) + (wid << 1) + nc) << 2) + kb) << 9));
  };

  // ---------------- stage x, h -> LDS bf16 (swizzled rows, 256 B/row) -------
  {
    const float4* xg = (const float4*)(x + row0 * 128);
    const float4* hg = (const float4*)(hprev + row0 * 128);
#pragma unroll
    for (int i = 0; i < 8; ++i) {
      int idx = i * 256 + tid;        // float4 index, 0..2047
      int r = idx >> 5;               // row 0..63
      int cbyte = (idx & 31) << 3;    // byte-in-row (col*2)
      int bo = (r * 256 + cbyte) ^ ((r & 7) << 4);
      float4 xv = xg[idx];
      float4 hv = hg[idx];
      uint2 xp, hp;
      xp.x = pk2(xv.x, xv.y); xp.y = pk2(xv.z, xv.w);
      hp.x = pk2(hv.x, hv.y); hp.y = pk2(hv.z, hv.w);
      *(uint2*)(smem + bo) = xp;
      *(uint2*)(smem + 16384 + bo) = hp;
    }
  }
  __syncthreads();

  auto ldsA = [&](const ushort* base, int mr, int k0) -> bf16x8 {
    int row = mr * 16 + l15;
    int bo = (row * 256 + (k0 + q * 8) * 2) ^ ((row & 7) << 4);
    return *(const bf16x8*)((const char*)base + bo);
  };

  // ---------------- r-pass: accr = x@Wr + h@Ur + br --------------------------
  f32x4 accr[4][2];
#pragma unroll
  for (int mr = 0; mr < 4; ++mr) {
    accr[mr][0] = splat4(brv0); accr[mr][1] = splat4(brv1);
  }
#pragma unroll
  for (int kb = 0; kb < 4; ++kb) {
    bf16x8 b0 = *wfrag(2, 0, kb), b1 = *wfrag(2, 1, kb);
    bf16x8 c0 = *wfrag(3, 0, kb), c1 = *wfrag(3, 1, kb);
#pragma unroll
    for (int mr = 0; mr < 4; ++mr) {
      bf16x8 ax = ldsA(xs, mr, kb * 32);
      bf16x8 ah = ldsA(hs, mr, kb * 32);
      accr[mr][0] = MFMA(ax, b0, accr[mr][0], 0, 0, 0);
      accr[mr][1] = MFMA(ax, b1, accr[mr][1], 0, 0, 0);
      accr[mr][0] = MFMA(ah, c0, accr[mr][0], 0, 0, 0);
      accr[mr][1] = MFMA(ah, c1, accr[mr][1], 0, 0, 0);
    }
  }

  // rh = sigmoid(accr) * h_prev -> rhs (no barrier needed: rhs is private space)
#pragma unroll
  for (int mr = 0; mr < 4; ++mr)
#pragma unroll
    for (int nc = 0; nc < 2; ++nc)
#pragma unroll
      for (int j = 0; j < 4; ++j) {
        int row = mr * 16 + q * 4 + j;
        int col = n0 + nc * 16 + l15;
        float rv = fsig(accr[mr][nc][j]);
        int bo = (row * 256 + col * 2) ^ ((row & 7) << 4);
        float hp = bf2f(*(const ushort*)((const char*)hs + bo));
        *(ushort*)((char*)rhs + bo) = f2bf(rv * hp);
      }

  __syncthreads();   // all waves' rh in rhs

  // ------- merged: accz = x@Wz + h@Uz + bz ; acch = x@Wh + rh@Uh + bh --------
  f32x4 accz[4][2], acch[4][2];
#pragma unroll
  for (int mr = 0; mr < 4; ++mr) {
    accz[mr][0] = splat4(bzv0); accz[mr][1] = splat4(bzv1);
    acch[mr][0] = splat4(bhv0); acch[mr][1] = splat4(bhv1);
  }
#pragma unroll
  for (int kb = 0; kb < 4; ++kb) {
    bf16x8 z0 = *wfrag(0, 0, kb), z1 = *wfrag(0, 1, kb);
    bf16x8 u0 = *wfrag(1, 0, kb), u1 = *wfrag(1, 1, kb);
    bf16x8 w0 = *wfrag(4, 0, kb), w1 = *wfrag(4, 1, kb);
    bf16x8 v0 = *wfrag(5, 0, kb), v1 = *wfrag(5, 1, kb);
#pragma unroll
    for (int mr = 0; mr < 4; ++mr) {
      bf16x8 ax = ldsA(xs, mr, kb * 32);
      bf16x8 ah = ldsA(hs, mr, kb * 32);
      bf16x8 ar = ldsA(rhs, mr, kb * 32);
      accz[mr][0] = MFMA(ax, z0, accz[mr][0], 0, 0, 0);
      accz[mr][1] = MFMA(ax, z1, accz[mr][1], 0, 0, 0);
      accz[mr][0] = MFMA(ah, u0, accz[mr][0], 0, 0, 0);
      accz[mr][1] = MFMA(ah, u1, accz[mr][1], 0, 0, 0);
      acch[mr][0] = MFMA(ax, w0, acch[mr][0], 0, 0, 0);
      acch[mr][1] = MFMA(ax, w1, acch[mr][1], 0, 0, 0);
      acch[mr][0] = MFMA(ar, v0, acch[mr][0], 0, 0, 0);
      acch[mr][1] = MFMA(ar, v1, acch[mr][1], 0, 0, 0);
    }
  }

  // ------- epilogue: h_t = hp + z*(hc - hp), into acch -----------------------
#pragma unroll
  for (int mr = 0; mr < 4; ++mr)
#pragma unroll
    for (int nc = 0; nc < 2; ++nc)
#pragma unroll
      for (int j = 0; j < 4; ++j) {
        int row = mr * 16 + q * 4 + j;
        int col = n0 + nc * 16 + l15;
        float hc = ftanh(acch[mr][nc][j]);
        float zv = fsig(accz[mr][nc][j]);
        int bo = (row * 256 + col * 2) ^ ((row & 7) << 4);
        float hp = bf2f(*(const ushort*)((const char*)hs + bo));
        acch[mr][nc][j] = hp + zv * (hc - hp);
      }

  __syncthreads();   // done reading xs/hs — reuse [0..32K) as f32 out-tile

  {
#pragma unroll
    for (int mr = 0; mr < 4; ++mr)
#pragma unroll
      for (int nc = 0; nc < 2; ++nc)
#pragma unroll
        for (int j = 0; j < 4; ++j) {
          int row = mr * 16 + q * 4 + j;
          int col = n0 + nc * 16 + l15;
          int bo = (row * 512 + col * 4) ^ ((row & 7) << 4);
          *(float*)(smem + bo) = acch[mr][nc][j];
        }
  }

  __syncthreads();

  // coalesced float4 stores
  {
#pragma unroll
    for (int i = 0; i < 8; ++i) {
      int idx = i * 256 + tid;        // float4 index 0..2047
      int row = idx >> 5;
      int c4 = idx & 31;
      int bo = (row * 512 + c4 * 16) ^ ((row & 7) << 4);
      float4 v = *(const float4*)(smem + bo);
      *(float4*)(out + (row0 + row) * 128 + c4 * 4) = v;
    }
  }
}

extern "C" void kernel_launch(void* const* d_in, const int* in_sizes, int n_in,
                              void* d_out, int out_size, void* d_ws, size_t ws_size,
                              hipStream_t stream) {
  const float* x  = (const float*)d_in[0];
  const float* h  = (const float*)d_in[1];
  const float* Wz = (const float*)d_in[2];
  const float* Uz = (const float*)d_in[3];
  const float* bz = (const float*)d_in[4];
  const float* Wr = (const float*)d_in[5];
  const float* Ur = (const float*)d_in[6];
  const float* br = (const float*)d_in[7];
  const float* Wh = (const float*)d_in[8];
  const float* Uh = (const float*)d_in[9];
  const float* bh = (const float*)d_in[10];
  ushort* wt = (ushort*)d_ws;   // 98304 bf16 = 192 KB packed fragment order

  hipLaunchKernelGGL(wtrans_kernel, dim3(384), dim3(256), 0, stream,
                     Wz, Uz, Wr, Ur, Wh, Uh, wt);
  hipLaunchKernelGGL(gru_kernel, dim3(GRU_B / BM), dim3(256), 0, stream,
                     x, h, wt, bz, br, bh, (float*)d_out);
}

// Round 7
// 56.892 us; speedup vs baseline: 1.5332x; 1.5332x over previous
//
#include <hip/hip_runtime.h>
#include <hip/hip_bf16.h>

typedef __attribute__((ext_vector_type(8))) short bf16x8;
typedef __attribute__((ext_vector_type(4))) float f32x4;

#define GRU_B 131072
#define BM 32
#define TPB 8            // row-tiles per persistent block
#define NBLK (GRU_B / (BM * TPB))   // 512 blocks

static __device__ __forceinline__ ushort f2bf(float f) {
  union { float f; unsigned u; } v; v.f = f;
  unsigned r = v.u + 0x7FFFu + ((v.u >> 16) & 1u);   // RNE
  return (ushort)(r >> 16);
}
static __device__ __forceinline__ float bf2f(ushort u) {
  union { unsigned u; float f; } v; v.u = ((unsigned)u) << 16;
  return v.f;
}
static __device__ __forceinline__ unsigned pk2(float a, float b) {
  float2 t; t.x = a; t.y = b;
  __hip_bfloat162 r = __float22bfloat162_rn(t);      // v_cvt_pk_bf16_f32
  union { __hip_bfloat162 b; unsigned u; } cv; cv.b = r;
  return cv.u;
}
static __device__ __forceinline__ float fsig(float x) {
  return __builtin_amdgcn_rcpf(1.0f + __expf(-x));
}
static __device__ __forceinline__ float ftanh(float x) {
  return 1.0f - 2.0f * __builtin_amdgcn_rcpf(1.0f + __expf(2.0f * x));
}
static __device__ __forceinline__ f32x4 splat4(float s) {
  f32x4 v = {s, s, s, s}; return v;
}

// Pack six 128x128 fp32 weight matrices into per-lane MFMA B-fragment order:
// chunk = ((mat*8 + cb)*4 + kb), 1KB each; within chunk lane*16B holds
// w[kb*32 + (lane>>4)*8 + e][cb*16 + (lane&15)], e=0..7, bf16.
// A B-frag load is ONE coalesced global_load_dwordx4 at chunk + lane*16.
__global__ void wtrans_kernel(const float* __restrict__ wz, const float* __restrict__ uz,
                              const float* __restrict__ wr, const float* __restrict__ ur,
                              const float* __restrict__ wh, const float* __restrict__ uh,
                              ushort* __restrict__ outw) {
  int f = blockIdx.x * 256 + threadIdx.x;          // 0..98303 (coalesced write)
  int mat = f >> 14;
  int rem = f & 16383;
  int chunk = rem >> 9;                            // 0..31
  int lane = (rem >> 3) & 63;
  int e = rem & 7;
  int cb = chunk >> 2, k0b = chunk & 3;
  int n = cb * 16 + (lane & 15);
  int k = k0b * 32 + (lane >> 4) * 8 + e;
  const float* src = (mat == 0) ? wz : (mat == 1) ? uz : (mat == 2) ? wr
                   : (mat == 3) ? ur : (mat == 4) ? wh : uh;
  outw[f] = f2bf(src[k * 128 + n]);
}

#define MFMA __builtin_amdgcn_mfma_f32_16x16x32_bf16

__global__ __launch_bounds__(512, 2) void gru_kernel(
    const float* __restrict__ x, const float* __restrict__ hprev,
    const ushort* __restrict__ wt,
    const float* __restrict__ bz, const float* __restrict__ br,
    const float* __restrict__ bh, float* __restrict__ out) {
  // 24 KB: xs[0..8K) hs[8K..16K) rhs[16K..24K) — single-buffered, reg-pipelined
  __shared__ __align__(16) char smem[24576];
  ushort* xs  = (ushort*)smem;
  ushort* hs  = (ushort*)(smem + 8192);
  ushort* rhs = (ushort*)(smem + 16384);

  const int tid = threadIdx.x;
  const int lane = tid & 63;
  const int wid = tid >> 6;          // 8 waves: 16 output cols each
  const int l15 = lane & 15;
  const int q = lane >> 4;
  const int n0 = wid * 16;

  // per-lane biases (folded into accumulator init)
  const float brv = br[n0 + l15];
  const float bzv = bz[n0 + l15];
  const float bhv = bh[n0 + l15];

  // -------- hoist ALL 24 weight fragments into registers (reused 8 tiles) ----
  const ushort* wlane = wt + (lane << 3);
  bf16x8 W[6][4];
#pragma unroll
  for (int mat = 0; mat < 6; ++mat)
#pragma unroll
    for (int kb = 0; kb < 4; ++kb)
      W[mat][kb] = *(const bf16x8*)(wlane + ((((mat << 3) + wid) << 2) + kb) * 512);

  auto ldsA = [&](const ushort* base, int mr, int k0) -> bf16x8 {
    int row = mr * 16 + l15;
    int bo = (row * 256 + (k0 + q * 8) * 2) ^ ((row & 7) << 4);
    return *(const bf16x8*)((const char*)base + bo);
  };

  const long tile0 = (long)blockIdx.x * TPB;

  // -------- prologue: load tile 0's x/h into registers -----------------------
  float4 px0, px1, ph0, ph1;
  {
    const float4* xg = (const float4*)(x + tile0 * BM * 128);
    const float4* hg = (const float4*)(hprev + tile0 * BM * 128);
    px0 = xg[tid]; px1 = xg[512 + tid];
    ph0 = hg[tid]; ph1 = hg[512 + tid];
  }

  for (int t = 0; t < TPB; ++t) {
    const long row0 = (tile0 + t) * BM;

    // ---- stage regs -> LDS bf16 (swizzled rows, 256 B/row) ----
    {
      int r0 = tid >> 5, cb0 = (tid & 31) << 3;
      int bo0 = (r0 * 256 + cb0) ^ ((r0 & 7) << 4);
      int idx1 = 512 + tid;
      int r1 = idx1 >> 5, cb1 = (idx1 & 31) << 3;
      int bo1 = (r1 * 256 + cb1) ^ ((r1 & 7) << 4);
      uint2 v;
      v.x = pk2(px0.x, px0.y); v.y = pk2(px0.z, px0.w);
      *(uint2*)(smem + bo0) = v;
      v.x = pk2(px1.x, px1.y); v.y = pk2(px1.z, px1.w);
      *(uint2*)(smem + bo1) = v;
      v.x = pk2(ph0.x, ph0.y); v.y = pk2(ph0.z, ph0.w);
      *(uint2*)(smem + 8192 + bo0) = v;
      v.x = pk2(ph1.x, ph1.y); v.y = pk2(ph1.z, ph1.w);
      *(uint2*)(smem + 8192 + bo1) = v;
    }
    __syncthreads();

    // ---- r-pass: accr = x@Wr + h@Ur + br (all weights reg-resident) ----
    f32x4 accr[2];
    accr[0] = splat4(brv); accr[1] = splat4(brv);
#pragma unroll
    for (int kb = 0; kb < 4; ++kb)
#pragma unroll
      for (int mr = 0; mr < 2; ++mr) {
        bf16x8 ax = ldsA(xs, mr, kb * 32);
        bf16x8 ah = ldsA(hs, mr, kb * 32);
        accr[mr] = MFMA(ax, W[2][kb], accr[mr], 0, 0, 0);
        accr[mr] = MFMA(ah, W[3][kb], accr[mr], 0, 0, 0);
      }

    // rh = sigmoid(accr) * h_prev -> rhs
#pragma unroll
    for (int mr = 0; mr < 2; ++mr)
#pragma unroll
      for (int j = 0; j < 4; ++j) {
        int row = mr * 16 + q * 4 + j;
        int col = n0 + l15;
        float rv = fsig(accr[mr][j]);
        int bo = (row * 256 + col * 2) ^ ((row & 7) << 4);
        float hp = bf2f(*(const ushort*)((const char*)hs + bo));
        *(ushort*)((char*)rhs + bo) = f2bf(rv * hp);
      }

    __syncthreads();   // all waves' rh visible

    // ---- prefetch tile t+1's x/h (latency hides under the merged pass) ----
    if (t + 1 < TPB) {
      const float4* xg = (const float4*)(x + (row0 + BM) * 128);
      const float4* hg = (const float4*)(hprev + (row0 + BM) * 128);
      px0 = xg[tid]; px1 = xg[512 + tid];
      ph0 = hg[tid]; ph1 = hg[512 + tid];
    }

    // ---- merged: accz = x@Wz + h@Uz + bz ; acch = x@Wh + rh@Uh + bh ----
    f32x4 accz[2], acch[2];
    accz[0] = splat4(bzv); accz[1] = splat4(bzv);
    acch[0] = splat4(bhv); acch[1] = splat4(bhv);
#pragma unroll
    for (int kb = 0; kb < 4; ++kb)
#pragma unroll
      for (int mr = 0; mr < 2; ++mr) {
        bf16x8 ax = ldsA(xs, mr, kb * 32);
        bf16x8 ah = ldsA(hs, mr, kb * 32);
        bf16x8 ar = ldsA(rhs, mr, kb * 32);
        accz[mr] = MFMA(ax, W[0][kb], accz[mr], 0, 0, 0);
        accz[mr] = MFMA(ah, W[1][kb], accz[mr], 0, 0, 0);
        acch[mr] = MFMA(ax, W[4][kb], acch[mr], 0, 0, 0);
        acch[mr] = MFMA(ar, W[5][kb], acch[mr], 0, 0, 0);
      }

    // ---- epilogue: h_t = hp + z*(hc - hp); direct 64B-segment stores ----
#pragma unroll
    for (int mr = 0; mr < 2; ++mr)
#pragma unroll
      for (int j = 0; j < 4; ++j) {
        int row = mr * 16 + q * 4 + j;
        int col = n0 + l15;
        float hc = ftanh(acch[mr][j]);
        float zv = fsig(accz[mr][j]);
        int bo = (row * 256 + col * 2) ^ ((row & 7) << 4);
        float hp = bf2f(*(const ushort*)((const char*)hs + bo));
        out[(row0 + row) * 128 + col] = hp + zv * (hc - hp);
      }

    __syncthreads();   // xs/hs/rhs free for next tile's stage
  }
}

extern "C" void kernel_launch(void* const* d_in, const int* in_sizes, int n_in,
                              void* d_out, int out_size, void* d_ws, size_t ws_size,
                              hipStream_t stream) {
  const float* x  = (const float*)d_in[0];
  const float* h  = (const float*)d_in[1];
  const float* Wz = (const float*)d_in[2];
  const float* Uz = (const float*)d_in[3];
  const float* bz = (const float*)d_in[4];
  const float* Wr = (const float*)d_in[5];
  const float* Ur = (const float*)d_in[6];
  const float* br = (const float*)d_in[7];
  const float* Wh = (const float*)d_in[8];
  const float* Uh = (const float*)d_in[9];
  const float* bh = (const float*)d_in[10];
  ushort* wt = (ushort*)d_ws;   // 98304 bf16 = 192 KB packed fragment order

  hipLaunchKernelGGL(wtrans_kernel, dim3(384), dim3(256), 0, stream,
                     Wz, Uz, Wr, Ur, Wh, Uh, wt);
  hipLaunchKernelGGL(gru_kernel, dim3(NBLK), dim3(512), 0, stream,
                     x, h, wt, bz, br, bh, (float*)d_out);
}